// Round 11
// baseline (1036.936 us; speedup 1.0000x reference)
//
#include <hip/hip_runtime.h>

#define DIM 64
#define PRESERVE 0.1f
#define SCHUNK 1024  // scan chunk = 256 threads x int4

typedef unsigned short bf16_t;

__device__ __forceinline__ float readlane_f(float v, int l) {
    return __int_as_float(__builtin_amdgcn_readlane(__float_as_int(v), l));
}
__device__ __forceinline__ float bf2f(bf16_t u) {
    return __uint_as_float(((unsigned)u) << 16);
}
__device__ __forceinline__ bf16_t f2bf(float f) {
    unsigned u = __float_as_uint(f);
    unsigned r = (u + 0x7FFFu + ((u >> 16) & 1u)) >> 16;  // RNE
    return (bf16_t)r;
}

// ---- software grid barrier (one pre-zeroed counter per barrier index) ----
// Valid only because the grid is fully co-resident: __launch_bounds__(256,4)
// -> <=128 VGPR -> 4 blocks/CU -> 1024 slots >= G=768, launched on an idle stream.
__device__ __forceinline__ void gbar(unsigned int* bar, int G) {
    __syncthreads();
    if (threadIdx.x == 0) {
        __threadfence();  // release: prior global writes visible device-wide
        __hip_atomic_fetch_add(bar, 1u, __ATOMIC_ACQ_REL, __HIP_MEMORY_SCOPE_AGENT);
        while (__hip_atomic_load(bar, __ATOMIC_ACQUIRE,
                                 __HIP_MEMORY_SCOPE_AGENT) < (unsigned)G)
            __builtin_amdgcn_s_sleep(2);
    }
    __syncthreads();
    __threadfence();  // acquire side: invalidate L1 so remote writes are seen
}

// ============ persistent front-end: hist -> scan -> fill||mm1 -> deg+scale ============
__global__ __launch_bounds__(256, 4) void k_mega(
        const int* __restrict__ row, const int* __restrict__ col,
        const float* __restrict__ ew, const float* __restrict__ x,
        const float* __restrict__ W1,
        int* __restrict__ cursor, unsigned int* __restrict__ bars,
        int* __restrict__ rank, int* __restrict__ offsets,
        int* __restrict__ blksum, int* __restrict__ blkoff,
        int2* __restrict__ sedge, float* __restrict__ dinv,
        float* __restrict__ temp, bf16_t* __restrict__ xs1,
        int N, int E) {
    const int G = gridDim.x;
    const int tid = threadIdx.x;
    const int gtid = blockIdx.x * 256 + tid;
    const int nthr = G * 256;
    const int nch = (N + SCHUNK - 1) / SCHUNK;

    // ---- P1: histogram + rank (cursor pre-zeroed by host memset).
    //      FULL grid, nothing co-scheduled: R10 showed stream traffic slows atomics.
    {
        int nvec = E >> 2;
        const int4* col4 = (const int4*)col;
        int4* rank4 = (int4*)rank;
        for (int t = gtid; t < nvec; t += nthr) {
            int4 c = col4[t];
            int4 r;
            r.x = atomicAdd(&cursor[c.x], 1);
            r.y = atomicAdd(&cursor[c.y], 1);
            r.z = atomicAdd(&cursor[c.z], 1);
            r.w = atomicAdd(&cursor[c.w], 1);
            rank4[t] = r;
        }
        for (int e = (nvec << 2) + gtid; e < E; e += nthr)
            rank[e] = atomicAdd(&cursor[col[e]], 1);
    }
    gbar(&bars[0], G);

    // ---- P2: per-chunk scan: offsets[i] = inclusive-in-chunk, blksum[ch] = total ----
    {
        __shared__ int s[256];
        for (int ch = blockIdx.x; ch < nch; ch += G) {
            int base = ch * SCHUNK + tid * 4;
            int a0 = 0, a1 = 0, a2 = 0, a3 = 0;
            if (base + 3 < N) {
                int4 v = *(const int4*)(cursor + base);
                a0 = v.x; a1 = v.y; a2 = v.z; a3 = v.w;
            } else {
                if (base < N) a0 = cursor[base];
                if (base + 1 < N) a1 = cursor[base + 1];
                if (base + 2 < N) a2 = cursor[base + 2];
            }
            int ts = a0 + a1 + a2 + a3;
            s[tid] = ts;
            __syncthreads();
            for (int off = 1; off < 256; off <<= 1) {
                int xv = (tid >= off) ? s[tid - off] : 0;
                __syncthreads();
                s[tid] += xv;
                __syncthreads();
            }
            int excl = s[tid] - ts;
            if (base < N) offsets[base] = excl + a0;
            if (base + 1 < N) offsets[base + 1] = excl + a0 + a1;
            if (base + 2 < N) offsets[base + 2] = excl + a0 + a1 + a2;
            if (base + 3 < N) offsets[base + 3] = excl + ts;
            if (tid == 255) blksum[ch] = s[255];
            __syncthreads();
        }
    }
    gbar(&bars[1], G);

    // ---- P3: block 0 scans chunk totals -> blkoff (exclusive), nch <= 512 ----
    if (blockIdx.x == 0) {
        __shared__ int p[256];
        int b0 = (2 * tid < nch) ? blksum[2 * tid] : 0;
        int b1 = (2 * tid + 1 < nch) ? blksum[2 * tid + 1] : 0;
        p[tid] = b0 + b1;
        __syncthreads();
        for (int off = 1; off < 256; off <<= 1) {
            int xv = (tid >= off) ? p[tid - off] : 0;
            __syncthreads();
            p[tid] += xv;
            __syncthreads();
        }
        int excl = p[tid] - (b0 + b1);
        if (2 * tid < nch) blkoff[2 * tid] = excl;
        if (2 * tid + 1 < nch) blkoff[2 * tid + 1] = excl + b0;
    }
    gbar(&bars[2], G);

    // ---- P4: finalize global exclusive offsets ----
    for (int i = gtid; i < N; i += nthr)
        offsets[i] = offsets[i] - cursor[i] + blkoff[i >> 10];  // SCHUNK=1024
    if (gtid == 0) offsets[N] = E;
    gbar(&bars[3], G);

    // ---- P5: fill CSR (blocks < Gf) || temp = x@W1 fp32 (rest); both atomic-free ----
    {
        const int Gf = G >> 1;
        if (blockIdx.x < Gf) {
            int t0 = blockIdx.x * 256 + tid;
            int nt = Gf * 256;
            int nvec = E >> 2;
            const int4* row4 = (const int4*)row;
            const int4* col4 = (const int4*)col;
            const float4* w4 = (const float4*)ew;
            const int4* rank4 = (const int4*)rank;
            for (int t = t0; t < nvec; t += nt) {
                int4 r = row4[t];
                int4 c = col4[t];
                float4 w = w4[t];
                int4 k = rank4[t];
                int2 pp;
                pp.x = r.x; pp.y = __float_as_int(w.x); sedge[offsets[c.x] + k.x] = pp;
                pp.x = r.y; pp.y = __float_as_int(w.y); sedge[offsets[c.y] + k.y] = pp;
                pp.x = r.z; pp.y = __float_as_int(w.z); sedge[offsets[c.z] + k.z] = pp;
                pp.x = r.w; pp.y = __float_as_int(w.w); sedge[offsets[c.w] + k.w] = pp;
            }
            for (int e = (nvec << 2) + t0; e < E; e += nt) {
                int2 pp;
                pp.x = row[e];
                pp.y = __float_as_int(ew[e]);
                sedge[offsets[col[e]] + rank[e]] = pp;
            }
        } else {
            int mb = blockIdx.x - Gf;
            int nmb = G - Gf;
            int lane = tid & 63;
            int waveId = mb * 4 + (tid >> 6);
            int nWaves = nmb * 4;
            float Wr[DIM];
#pragma unroll
            for (int k = 0; k < DIM; ++k) Wr[k] = W1[k * DIM + lane];
            for (int r0 = waveId * 4; r0 < N; r0 += nWaves * 4) {
                if (r0 + 3 < N) {
                    float x0 = x[(size_t)(r0 + 0) * DIM + lane];
                    float x1 = x[(size_t)(r0 + 1) * DIM + lane];
                    float x2 = x[(size_t)(r0 + 2) * DIM + lane];
                    float x3 = x[(size_t)(r0 + 3) * DIM + lane];
                    float a0 = 0.f, a1 = 0.f, a2 = 0.f, a3 = 0.f;
#pragma unroll
                    for (int k = 0; k < DIM; ++k) {
                        float w = Wr[k];
                        a0 += readlane_f(x0, k) * w;
                        a1 += readlane_f(x1, k) * w;
                        a2 += readlane_f(x2, k) * w;
                        a3 += readlane_f(x3, k) * w;
                    }
                    temp[(size_t)(r0 + 0) * DIM + lane] = a0;
                    temp[(size_t)(r0 + 1) * DIM + lane] = a1;
                    temp[(size_t)(r0 + 2) * DIM + lane] = a2;
                    temp[(size_t)(r0 + 3) * DIM + lane] = a3;
                } else {
                    for (int r = r0; r < N; ++r) {
                        float xv = x[(size_t)r * DIM + lane];
                        float a = 0.f;
#pragma unroll
                        for (int k = 0; k < DIM; ++k) a += readlane_f(xv, k) * Wr[k];
                        temp[(size_t)r * DIM + lane] = a;
                    }
                }
            }
        }
    }
    gbar(&bars[4], G);

    // ---- P6: deg -> dinv -> xs1 = bf16(temp * dinv) (wave per node) ----
    {
        int lane = tid & 63;
        int wv = blockIdx.x * 4 + (tid >> 6);
        int nW = G * 4;
        for (int c = wv; c < N; c += nW) {
            int beg = offsets[c];
            int end = offsets[c + 1];
            float s = 0.f;
            for (int j = beg + lane; j < end; j += 64) s += __int_as_float(sedge[j].y);
            for (int off = 32; off > 0; off >>= 1) s += __shfl_xor(s, off);
            float d = 1.0f + s;
            float di = (d > 0.f) ? rsqrtf(d) : 0.f;
            if (lane == 0) dinv[c] = di;
            xs1[(size_t)c * DIM + lane] = f2bf(temp[(size_t)c * DIM + lane] * di);
        }
    }
}

// ---------- xs = bf16( (x @ W) * dinv[row] ) — layer-2 matmul ----------
__global__ __launch_bounds__(256) void k_mm(
        const float* __restrict__ x, const float* __restrict__ W,
        const float* __restrict__ dinv, bf16_t* __restrict__ xs, int n) {
    int tid = threadIdx.x;
    int lane = tid & 63;
    int waveId = blockIdx.x * 4 + (tid >> 6);
    int nWaves = gridDim.x * 4;

    float Wr[DIM];
#pragma unroll
    for (int k = 0; k < DIM; ++k) Wr[k] = W[k * DIM + lane];

    for (int r0 = waveId * 4; r0 < n; r0 += nWaves * 4) {
        if (r0 + 3 < n) {
            float x0 = x[(size_t)(r0 + 0) * DIM + lane];
            float x1 = x[(size_t)(r0 + 1) * DIM + lane];
            float x2 = x[(size_t)(r0 + 2) * DIM + lane];
            float x3 = x[(size_t)(r0 + 3) * DIM + lane];
            float a0 = 0.f, a1 = 0.f, a2 = 0.f, a3 = 0.f;
#pragma unroll
            for (int k = 0; k < DIM; ++k) {
                float w = Wr[k];
                a0 += readlane_f(x0, k) * w;
                a1 += readlane_f(x1, k) * w;
                a2 += readlane_f(x2, k) * w;
                a3 += readlane_f(x3, k) * w;
            }
            xs[(size_t)(r0 + 0) * DIM + lane] = f2bf(a0 * dinv[r0 + 0]);
            xs[(size_t)(r0 + 1) * DIM + lane] = f2bf(a1 * dinv[r0 + 1]);
            xs[(size_t)(r0 + 2) * DIM + lane] = f2bf(a2 * dinv[r0 + 2]);
            xs[(size_t)(r0 + 3) * DIM + lane] = f2bf(a3 * dinv[r0 + 3]);
        } else {
            for (int r = r0; r < n; ++r) {
                float xv = x[(size_t)r * DIM + lane];
                float a = 0.f;
#pragma unroll
                for (int k = 0; k < DIM; ++k) a += readlane_f(xv, k) * Wr[k];
                xs[(size_t)r * DIM + lane] = f2bf(a * dinv[r]);
            }
        }
    }
}

// ---------- gather (wave per node, lane = dim): xs pre-scaled by dinv[row], raw w ----------
// out[c] = 0.9*( dinv[c]*( xs[c] + sum_e w_e*xs[r_e] ) + b ) + 0.1*xprev[c]
__global__ __launch_bounds__(256) void k_gather(
        const bf16_t* __restrict__ xs, const int* __restrict__ offsets,
        const int2* __restrict__ sedge, const float* __restrict__ dinv,
        const float* __restrict__ b, const float* __restrict__ xprev,
        float* __restrict__ out, int n) {
    int lane = threadIdx.x & 63;
    int c = blockIdx.x * 4 + (threadIdx.x >> 6);
    if (c >= n) return;
    float di = dinv[c];
    float acc = bf2f(xs[(size_t)c * DIM + lane]);  // = dinv[c]*xw[c]
    int beg = offsets[c];
    int end = offsets[c + 1];
    for (int b0 = beg; b0 < end; b0 += 64) {
        int m = end - b0;
        if (m > 64) m = 64;
        int r_l = 0, w_l = 0;
        if (lane < m) {
            int2 p = sedge[b0 + lane];  // coalesced batch load
            r_l = p.x;
            w_l = p.y;
        }
        int j = 0;
        for (; j + 3 < m; j += 4) {
            int r0 = __builtin_amdgcn_readlane(r_l, j);
            int r1 = __builtin_amdgcn_readlane(r_l, j + 1);
            int r2 = __builtin_amdgcn_readlane(r_l, j + 2);
            int r3 = __builtin_amdgcn_readlane(r_l, j + 3);
            float w0 = readlane_f(__int_as_float(w_l), j);
            float w1 = readlane_f(__int_as_float(w_l), j + 1);
            float w2 = readlane_f(__int_as_float(w_l), j + 2);
            float w3 = readlane_f(__int_as_float(w_l), j + 3);
            acc += bf2f(xs[(size_t)r0 * DIM + lane]) * w0;
            acc += bf2f(xs[(size_t)r1 * DIM + lane]) * w1;
            acc += bf2f(xs[(size_t)r2 * DIM + lane]) * w2;
            acc += bf2f(xs[(size_t)r3 * DIM + lane]) * w3;
        }
        for (; j < m; ++j) {
            int r0 = __builtin_amdgcn_readlane(r_l, j);
            float w0 = readlane_f(__int_as_float(w_l), j);
            acc += bf2f(xs[(size_t)r0 * DIM + lane]) * w0;
        }
    }
    float v = (1.0f - PRESERVE) * (acc * di + b[lane])
            + PRESERVE * xprev[(size_t)c * DIM + lane];
    out[(size_t)c * DIM + lane] = v;
}

extern "C" void kernel_launch(void* const* d_in, const int* in_sizes, int n_in,
                              void* d_out, int out_size, void* d_ws, size_t ws_size,
                              hipStream_t stream) {
    const float* x  = (const float*)d_in[0];
    const int*   ei = (const int*)d_in[1];
    const float* ew = (const float*)d_in[2];
    const float* W1 = (const float*)d_in[3];
    const float* b1 = (const float*)d_in[4];
    const float* W2 = (const float*)d_in[5];
    const float* b2 = (const float*)d_in[6];

    const int N = in_sizes[0] / DIM;      // 100000
    const int E = in_sizes[2];            // 1250000
    const int* row = ei;
    const int* col = ei + E;

    // workspace layout (all region sizes multiples of 16B; base 16B-aligned)
    int2* sedge   = (int2*)d_ws;                          // E      (10.0 MB)
    float* dinv   = (float*)(sedge + E);                  // N
    float* temp   = dinv + N;                             // N*DIM fp32 (25.6 MB)
    bf16_t* xs1   = (bf16_t*)(temp + (size_t)N * DIM);    // N*DIM bf16
    bf16_t* xs2   = xs1 + (size_t)N * DIM;                // N*DIM bf16
    int* rank     = (int*)(xs2 + (size_t)N * DIM);        // E
    int* cursor   = rank + E;                             // N      <- memset start
    unsigned int* bars = (unsigned int*)(cursor + N);     // 32     <- memset
    int* offsets  = (int*)(bars + 32);                    // N+1
    int* blksum   = offsets + N + 1;                      // 512
    int* blkoff   = blksum + 512;                         // 512

    const int B = 256;
    const int G = 768;        // co-resident under __launch_bounds__(256,4)
    const int nblkG = (N + 3) / 4;
    const int nblkMM = 1024;

    // 1) zero cursor + barrier counters (graph-capturable)
    hipMemsetAsync(cursor, 0, (size_t)(N + 32) * sizeof(int), stream);

    // 2) persistent front-end: hist -> scan -> fill||mm1 -> deg+scale
    k_mega<<<G, B, 0, stream>>>(row, col, ew, x, W1,
                                cursor, bars, rank, offsets, blksum, blkoff,
                                sedge, dinv, temp, xs1, N, E);

    // 3) layer 1 gather -> temp (fp32)
    k_gather<<<nblkG, B, 0, stream>>>(xs1, offsets, sedge, dinv, b1, x, temp, N);
    // 4) layer 2 matmul: xs2 = bf16((temp @ W2) * dinv)
    k_mm<<<nblkMM, B, 0, stream>>>(temp, W2, dinv, xs2, N);
    // 5) layer 2 gather -> d_out
    k_gather<<<nblkG, B, 0, stream>>>(xs2, offsets, sedge, dinv, b2, temp,
                                      (float*)d_out, N);
}